// Round 2
// baseline (4889.329 us; speedup 1.0000x reference)
//
#include <hip/hip_runtime.h>
#include <math.h>

#define SEQ 197
#define BATCH 32
#define DIM 256
#define NHEAD 8
#define HDIM 32
#define NEXP 8
#define NLAYER 4
#define FFDIM 1024
#define NCLS 1000
#define NPATCH 196
#define TOK (BATCH * SEQ) /* 6304 */
#define CAP 13120         /* 2*TOK + 8*64 segment padding */
#define YB 99             /* ceil(TOK/64) */
#define YB128 50          /* ceil(TOK/128) */

// ---------------------------------------------------------------- im2col ----
__global__ __launch_bounds__(256) void k_im2col(const float* __restrict__ x,
                                                float* __restrict__ Apat) {
  int idx = blockIdx.x * 256 + threadIdx.x;
  if (idx >= BATCH * NPATCH * 768) return;
  int cpp = idx % 768;
  int m = idx / 768;
  int n = m % NPATCH;
  int b = m / NPATCH;
  int c = cpp >> 8;
  int py = (cpp >> 4) & 15;
  int px = cpp & 15;
  int gy = n / 14, gx = n % 14;
  Apat[idx] = x[(((size_t)b * 3 + c) * 224 + gy * 16 + py) * 224 + gx * 16 + px];
}

// ------------------------------------------------------------- unified GEMM -
// BMx64x16 tile, 256 threads, (BM/16)x4 per thread, float4 staging,
// register-prefetch pipeline. blockIdx.z = expert slot ez, e = ebase+ez.
// flags bit0 = segmented rows (off_e/cnt_e), bit1 = gather A row via ptok.
// AFF: per-expert affine on A: a = fma(a, gsc[e*K+k], gof[e*K+k]).
// mode 0: out[row] = v            (seg: row=gr; dense: row=ez*M+r)
// mode 1: out[gr]  = v + R[tok]
// mode 2: out[gr]  = gelu(v)
// mode 3: atomicAdd(out[tok], PW[gr]*(X2[gr]+v))
template <int BM, bool AFF>
__global__ __launch_bounds__(256) void k_gemm_t(
    const float* __restrict__ A, const float* __restrict__ W,
    const float* __restrict__ bias, const float* __restrict__ gsc,
    const float* __restrict__ gof, const float* __restrict__ R,
    const float* __restrict__ X2, const float* __restrict__ PW,
    const int* __restrict__ ptok, const int* __restrict__ off_e,
    const int* __restrict__ cnt_e, float* __restrict__ out, int M, int N,
    int K, int Wld, int wcol, int bstride, int ebase, int mode, int flags) {
  const int TM = BM / 16;
  const int NF = BM / 64;
  __shared__ float As[16][BM + 4];
  __shared__ float Bs[16][68];
  int ez = blockIdx.z;
  int e = ebase + ez;
  bool seg = (flags & 1) != 0;
  int rows = seg ? cnt_e[e] : M;
  int row0 = blockIdx.y * BM;
  if (row0 >= rows) return;
  int col0 = blockIdx.x * 64;
  int tid = threadIdx.x;
  int base = seg ? off_e[e] : 0;
  const float* Wp = W + (size_t)e * K * Wld + wcol;
  const float* bp = bias + (size_t)e * bstride + wcol;

  // staging maps
  const float* aptr[NF];
  const float* gptr[NF];
  const float* optr[NF];
  float amask[NF];
  int arr[NF], akq[NF];
#pragma unroll
  for (int u = 0; u < NF; ++u) {
    int f = tid + 256 * u;
    int rr = f >> 2;
    int kq = (f & 3) * 4;
    arr[u] = rr;
    akq[u] = kq;
    int r = row0 + rr;
    bool val = r < rows;
    int rc = val ? r : rows - 1; /* rows>=1 here */
    int gr = base + rc;
    int arow = seg ? ((flags & 2) ? ptok[gr] : gr) : rc;
    aptr[u] = A + (size_t)arow * K + kq;
    amask[u] = val ? 1.f : 0.f;
    if (AFF) {
      gptr[u] = gsc + (size_t)e * K + kq;
      optr[u] = gof + (size_t)e * K + kq;
    }
  }
  int bkk = tid >> 4;
  int bn4 = (tid & 15) * 4;
  const float* bptr = Wp + (size_t)bkk * Wld + col0 + bn4;

  float4 aL[NF], gL[NF], oL[NF], bT;
  // prologue load
#pragma unroll
  for (int u = 0; u < NF; ++u) {
    aL[u] = *(const float4*)aptr[u];
    if (AFF) {
      gL[u] = *(const float4*)gptr[u];
      oL[u] = *(const float4*)optr[u];
    }
  }
  bT = *(const float4*)bptr;
  // prologue store
#pragma unroll
  for (int u = 0; u < NF; ++u) {
    float4 v = aL[u];
    if (AFF) {
      v.x = fmaf(v.x, gL[u].x, oL[u].x);
      v.y = fmaf(v.y, gL[u].y, oL[u].y);
      v.z = fmaf(v.z, gL[u].z, oL[u].z);
      v.w = fmaf(v.w, gL[u].w, oL[u].w);
    }
    float mk = amask[u];
    As[akq[u] + 0][arr[u]] = v.x * mk;
    As[akq[u] + 1][arr[u]] = v.y * mk;
    As[akq[u] + 2][arr[u]] = v.z * mk;
    As[akq[u] + 3][arr[u]] = v.w * mk;
  }
  *(float4*)&Bs[bkk][bn4] = bT;
  __syncthreads();

  int ty = tid >> 4, tx = tid & 15;
  float acc[TM][4] = {};
  int nk0 = K >> 4;
  for (int it = 0; it < nk0; ++it) {
    bool more = (it + 1) < nk0;
    if (more) { /* issue next-tile loads; wait lands at the LDS write below */
#pragma unroll
      for (int u = 0; u < NF; ++u) {
        aptr[u] += 16;
        aL[u] = *(const float4*)aptr[u];
        if (AFF) {
          gptr[u] += 16;
          optr[u] += 16;
          gL[u] = *(const float4*)gptr[u];
          oL[u] = *(const float4*)optr[u];
        }
      }
      bptr += (size_t)16 * Wld;
      bT = *(const float4*)bptr;
    }
#pragma unroll
    for (int k = 0; k < 16; ++k) {
      float a[TM], bb[4];
#pragma unroll
      for (int i = 0; i < TM; ++i) a[i] = As[k][ty * TM + i];
#pragma unroll
      for (int j = 0; j < 4; ++j) bb[j] = Bs[k][tx * 4 + j];
#pragma unroll
      for (int i = 0; i < TM; ++i)
#pragma unroll
        for (int j = 0; j < 4; ++j) acc[i][j] = fmaf(a[i], bb[j], acc[i][j]);
    }
    __syncthreads();
    if (more) {
#pragma unroll
      for (int u = 0; u < NF; ++u) {
        float4 v = aL[u];
        if (AFF) {
          v.x = fmaf(v.x, gL[u].x, oL[u].x);
          v.y = fmaf(v.y, gL[u].y, oL[u].y);
          v.z = fmaf(v.z, gL[u].z, oL[u].z);
          v.w = fmaf(v.w, gL[u].w, oL[u].w);
        }
        float mk = amask[u];
        As[akq[u] + 0][arr[u]] = v.x * mk;
        As[akq[u] + 1][arr[u]] = v.y * mk;
        As[akq[u] + 2][arr[u]] = v.z * mk;
        As[akq[u] + 3][arr[u]] = v.w * mk;
      }
      *(float4*)&Bs[bkk][bn4] = bT;
      __syncthreads();
    }
  }
  // epilogue
#pragma unroll
  for (int i = 0; i < TM; ++i) {
    int r = row0 + ty * TM + i;
    if (r >= rows) continue;
    int gr = base + r;
#pragma unroll
    for (int j = 0; j < 4; ++j) {
      int col = col0 + tx * 4 + j;
      float v = acc[i][j] + bp[col];
      if (mode == 0) {
        size_t orow = seg ? (size_t)gr : (size_t)ez * M + r;
        out[orow * N + col] = v;
      } else if (mode == 1) {
        int t = ptok[gr];
        out[(size_t)gr * N + col] = v + R[(size_t)t * N + col];
      } else if (mode == 2) {
        out[(size_t)gr * N + col] =
            0.5f * v * (1.f + erff(v * 0.70710678118654752f));
      } else {
        int t = ptok[gr];
        atomicAdd(&out[(size_t)t * N + col],
                  PW[gr] * (X2[(size_t)gr * N + col] + v));
      }
    }
  }
}

// ------------------------------------------------------------- assemble h ---
__global__ __launch_bounds__(256) void k_assemble(const float* __restrict__ tmp,
                                                  const float* __restrict__ cls,
                                                  const float* __restrict__ pos,
                                                  float* __restrict__ h) {
  int idx = blockIdx.x * 256 + threadIdx.x;
  if (idx >= TOK * DIM) return;
  int d = idx & 255;
  int t = idx >> 8;
  int s = t % SEQ;
  int b = t / SEQ;
  float v = (s == 0) ? cls[d] : tmp[((size_t)b * NPATCH + s - 1) * DIM + d];
  h[idx] = v + pos[s * DIM + d];
}

// ------------------------------------------------------------------ router --
__global__ __launch_bounds__(64) void k_router(
    const float* __restrict__ h, const float* __restrict__ rw,
    const float* __restrict__ rb, int* __restrict__ cnt_eb,
    int* __restrict__ tmp_s, float* __restrict__ tmp_w) {
  int t = blockIdx.x;
  int lane = threadIdx.x;
  float hv[4];
  const float* hp = h + (size_t)t * DIM + lane * 4;
#pragma unroll
  for (int i = 0; i < 4; i++) hv[i] = hp[i];
  float lg[8];
#pragma unroll
  for (int e = 0; e < 8; e++) {
    float p = 0.f;
#pragma unroll
    for (int i = 0; i < 4; i++) p = fmaf(hv[i], rw[(lane * 4 + i) * 8 + e], p);
#pragma unroll
    for (int off = 32; off; off >>= 1) p += __shfl_down(p, off);
    lg[e] = p;
  }
  if (lane == 0) {
#pragma unroll
    for (int e = 0; e < 8; e++) lg[e] += rb[e];
    float mx = lg[0];
#pragma unroll
    for (int e = 1; e < 8; e++) mx = fmaxf(mx, lg[e]);
    float pr[8];
#pragma unroll
    for (int e = 0; e < 8; e++) pr[e] = expf(lg[e] - mx);
    int i0 = 0;
#pragma unroll
    for (int e = 1; e < 8; e++)
      if (pr[e] > pr[i0]) i0 = e;
    int i1 = -1;
#pragma unroll
    for (int e = 0; e < 8; e++)
      if (e != i0 && (i1 < 0 || pr[e] > pr[i1])) i1 = e;
    float wsum = pr[i0] + pr[i1];
    int b = t / SEQ, s = t - b * SEQ;
    int eb0 = i0 * 32 + b;
    int p0 = atomicAdd(&cnt_eb[eb0], 1);
    tmp_s[eb0 * SEQ + p0] = s;
    tmp_w[eb0 * SEQ + p0] = pr[i0] / wsum;
    int eb1 = i1 * 32 + b;
    int p1 = atomicAdd(&cnt_eb[eb1], 1);
    tmp_s[eb1 * SEQ + p1] = s;
    tmp_w[eb1 * SEQ + p1] = pr[i1] / wsum;
  }
}

// --------------------------------------------------------------- scan -------
__global__ __launch_bounds__(64) void k_scan(const int* __restrict__ cnt_eb,
                                             int* __restrict__ off_eb,
                                             int* __restrict__ off_e,
                                             int* __restrict__ cnt_e) {
  if (threadIdx.x == 0 && blockIdx.x == 0) {
    int g = 0;
    for (int e = 0; e < 8; e++) {
      off_e[e] = g;
      int ce = 0;
      for (int b = 0; b < 32; b++) {
        off_eb[e * 32 + b] = g + ce;
        ce += cnt_eb[e * 32 + b];
      }
      cnt_e[e] = ce;
      g += (ce + 63) & ~63;
    }
  }
}

__global__ __launch_bounds__(256) void k_scatter(
    const int* __restrict__ cnt_eb, const int* __restrict__ off_eb,
    const int* __restrict__ tmp_s, const float* __restrict__ tmp_w,
    int* __restrict__ ptok, float* __restrict__ pw) {
  int eb = blockIdx.x;
  int b = eb & 31;
  int c = cnt_eb[eb];
  int o = off_eb[eb];
  for (int i = threadIdx.x; i < c; i += 256) {
    ptok[o + i] = b * SEQ + tmp_s[eb * SEQ + i];
    pw[o + i] = tmp_w[eb * SEQ + i];
  }
}

// -------------------------------------------------------------- layernorm ---
__global__ __launch_bounds__(256) void k_ln_noaff(const float* __restrict__ X,
                                                  float* __restrict__ Y) {
  int t = blockIdx.x;
  int d = threadIdx.x;
  float v = X[(size_t)t * DIM + d];
  __shared__ float red[4];
  float s = v;
#pragma unroll
  for (int o = 32; o; o >>= 1) s += __shfl_down(s, o);
  if ((d & 63) == 0) red[d >> 6] = s;
  __syncthreads();
  float mean = (red[0] + red[1] + red[2] + red[3]) * (1.f / 256.f);
  __syncthreads();
  float c = v - mean;
  float s2 = c * c;
#pragma unroll
  for (int o = 32; o; o >>= 1) s2 += __shfl_down(s2, o);
  if ((d & 63) == 0) red[d >> 6] = s2;
  __syncthreads();
  float var = (red[0] + red[1] + red[2] + red[3]) * (1.f / 256.f);
  Y[(size_t)t * DIM + d] = c * rsqrtf(var + 1e-5f);
}

__global__ __launch_bounds__(256) void k_ln_seg(
    const float* __restrict__ X, const float* __restrict__ g,
    const float* __restrict__ bta, float* __restrict__ Y,
    const int* __restrict__ off_e, const int* __restrict__ cnt_e) {
  int e = blockIdx.y;
  int cnt = cnt_e[e];
  int base = off_e[e];
  int d = threadIdx.x;
  float gv = g[e * DIM + d];
  float bv = bta[e * DIM + d];
  __shared__ float red[4];
  for (int r = blockIdx.x; r < cnt; r += gridDim.x) {
    size_t gr = (size_t)(base + r);
    float v = X[gr * DIM + d];
    float s = v;
#pragma unroll
    for (int o = 32; o; o >>= 1) s += __shfl_down(s, o);
    if ((d & 63) == 0) red[d >> 6] = s;
    __syncthreads();
    float mean = (red[0] + red[1] + red[2] + red[3]) * (1.f / 256.f);
    __syncthreads();
    float c = v - mean;
    float s2 = c * c;
#pragma unroll
    for (int o = 32; o; o >>= 1) s2 += __shfl_down(s2, o);
    if ((d & 63) == 0) red[d >> 6] = s2;
    __syncthreads();
    float var = (red[0] + red[1] + red[2] + red[3]) * (1.f / 256.f);
    Y[gr * DIM + d] = c * rsqrtf(var + 1e-5f) * gv + bv;
    __syncthreads();
  }
}

// -------------------------------------------------------------- attention ---
__global__ __launch_bounds__(256) void k_attn(
    const float* __restrict__ qc, const float* __restrict__ kv,
    float* __restrict__ oc, const int* __restrict__ cnt_eb,
    const int* __restrict__ off_eb, int ebase) {
  int bx = blockIdx.x;
  int hh = bx & 7;
  int b = (bx >> 3) & 31;
  int ez = bx >> 8;
  int eb = (ebase + ez) * 32 + b;
  int cnt = cnt_eb[eb];
  if (cnt == 0) return;
  int off = off_eb[eb];
  __shared__ float Ks[SEQ][HDIM];
  __shared__ float Vs[SEQ][HDIM];
  const float* base = kv + ((size_t)ez * TOK + (size_t)b * SEQ) * 512;
  int tid = threadIdx.x;
  for (int i = tid; i < SEQ * 8; i += 256) {
    int row = i >> 3, c4 = (i & 7) * 4;
    const float* kp = base + (size_t)row * 512 + hh * HDIM + c4;
    *(float4*)&Ks[row][c4] = *(const float4*)kp;
    *(float4*)&Vs[row][c4] = *(const float4*)(kp + 256);
  }
  __syncthreads();
  int q = tid;
  if (q >= cnt) return;
  float qv[HDIM];
  const float* qp = qc + (size_t)(off + q) * DIM + hh * HDIM;
#pragma unroll
  for (int i = 0; i < 8; i++) {
    float4 t = *(const float4*)(qp + i * 4);
    qv[i * 4 + 0] = t.x;
    qv[i * 4 + 1] = t.y;
    qv[i * 4 + 2] = t.z;
    qv[i * 4 + 3] = t.w;
  }
  float m = -1e30f, l = 0.f;
  float acc[HDIM] = {};
  for (int j = 0; j < SEQ; ++j) {
    float s = 0.f;
#pragma unroll
    for (int d = 0; d < HDIM; ++d) s = fmaf(qv[d], Ks[j][d], s);
    s *= 0.17677669529663687f; /* 1/sqrt(32) */
    float e2;
    if (s > m) {
      float f = expf(m - s);
      l *= f;
#pragma unroll
      for (int d = 0; d < HDIM; ++d) acc[d] *= f;
      m = s;
      e2 = 1.f;
    } else {
      e2 = expf(s - m);
    }
    l += e2;
#pragma unroll
    for (int d = 0; d < HDIM; ++d) acc[d] = fmaf(e2, Vs[j][d], acc[d]);
  }
  float inv = 1.f / l;
  float* op = oc + (size_t)(off + q) * DIM + hh * HDIM;
#pragma unroll
  for (int i = 0; i < 8; i++) {
    float4 t;
    t.x = acc[i * 4 + 0] * inv;
    t.y = acc[i * 4 + 1] * inv;
    t.z = acc[i * 4 + 2] * inv;
    t.w = acc[i * 4 + 3] * inv;
    *(float4*)(op + i * 4) = t;
  }
}

// ------------------------------------------------------------- final head ---
__global__ __launch_bounds__(256) void k_head(const float* __restrict__ h,
                                              const float* __restrict__ ng,
                                              const float* __restrict__ nb,
                                              const float* __restrict__ hw,
                                              const float* __restrict__ hb,
                                              float* __restrict__ out) {
  int b = blockIdx.x;
  int d = threadIdx.x;
  float v = h[(size_t)b * SEQ * DIM + d];
  __shared__ float red[4];
  __shared__ float hls[DIM];
  float s = v;
#pragma unroll
  for (int off = 32; off; off >>= 1) s += __shfl_down(s, off);
  if ((d & 63) == 0) red[d >> 6] = s;
  __syncthreads();
  float mean = (red[0] + red[1] + red[2] + red[3]) * (1.f / 256.f);
  __syncthreads();
  float c = v - mean;
  float s2 = c * c;
#pragma unroll
  for (int off = 32; off; off >>= 1) s2 += __shfl_down(s2, off);
  if ((d & 63) == 0) red[d >> 6] = s2;
  __syncthreads();
  float var = (red[0] + red[1] + red[2] + red[3]) * (1.f / 256.f);
  hls[d] = c * rsqrtf(var + 1e-5f) * ng[d] + nb[d];
  __syncthreads();
  for (int j = d; j < NCLS; j += 256) {
    float sdot = hb[j];
    for (int k2 = 0; k2 < DIM; k2++)
      sdot = fmaf(hls[k2], hw[(size_t)k2 * NCLS + j], sdot);
    out[(size_t)b * NCLS + j] = sdot;
  }
}

// ---------------------------------------------------------------- launch ----
extern "C" void kernel_launch(void* const* d_in, const int* in_sizes, int n_in,
                              void* d_out, int out_size, void* d_ws,
                              size_t ws_size, hipStream_t stream) {
  const float* x = (const float*)d_in[0];
  const float* patch_w = (const float*)d_in[1];
  const float* patch_b = (const float*)d_in[2];
  const float* cls_token = (const float*)d_in[3];
  const float* pos_embed = (const float*)d_in[4];
  const float* router_w = (const float*)d_in[5];
  const float* router_b = (const float*)d_in[6];
  const float* ln1_g = (const float*)d_in[7];
  const float* ln1_b = (const float*)d_in[8];
  const float* qkv_w = (const float*)d_in[9];
  const float* qkv_b = (const float*)d_in[10];
  const float* proj_w = (const float*)d_in[11];
  const float* proj_b = (const float*)d_in[12];
  const float* ln2_g = (const float*)d_in[13];
  const float* ln2_b = (const float*)d_in[14];
  const float* fc1_w = (const float*)d_in[15];
  const float* fc1_b = (const float*)d_in[16];
  const float* fc2_w = (const float*)d_in[17];
  const float* fc2_b = (const float*)d_in[18];
  const float* norm_g = (const float*)d_in[19];
  const float* norm_b = (const float*)d_in[20];
  const float* head_w = (const float*)d_in[21];
  const float* head_b = (const float*)d_in[22];

  float* ws = (float*)d_ws;
  size_t off = 0;
  float* xhat = ws + off; off += (size_t)TOK * DIM;
  float* hbuf = ws + off; off += (size_t)TOK * DIM;
  float* accb = ws + off; off += (size_t)TOK * DIM;
  float* qc   = ws + off; off += (size_t)CAP * DIM;   /* also hln (aliased) */
  float* oc   = ws + off; off += (size_t)CAP * DIM;
  float* x2c  = ws + off; off += (size_t)CAP * DIM;
  float* ffc  = ws + off; off += (size_t)CAP * FFDIM; /* also im2col + kv4 */
  float* pwb  = ws + off; off += CAP;
  float* tmpw = ws + off; off += 256 * SEQ;
  int* ptok   = (int*)(ws + off); off += CAP;
  int* tmps   = (int*)(ws + off); off += 256 * SEQ;
  int* cnt_eb = (int*)(ws + off); off += 256;
  int* off_eb = (int*)(ws + off); off += 256;
  int* off_e  = (int*)(ws + off); off += 8;
  int* cnt_e  = (int*)(ws + off); off += 8;
  float* kv4 = ffc;   /* 4*TOK*512 = 12.9M floats <= CAP*FFDIM = 13.4M */
  float* hlnc = qc;   /* qc dead after attention; hln live ln2->fc1 */

  // ---- patch embed ----
  int tot = BATCH * NPATCH * 768;
  k_im2col<<<(tot + 255) / 256, 256, 0, stream>>>(x, ffc);
  k_gemm_t<128, false><<<dim3(4, 49, 1), 256, 0, stream>>>(
      ffc, patch_w, patch_b, nullptr, nullptr, nullptr, nullptr, nullptr,
      nullptr, nullptr, nullptr, qc, BATCH * NPATCH, DIM, 768, DIM, 0, 0, 0, 0,
      0);
  k_assemble<<<(TOK * DIM + 255) / 256, 256, 0, stream>>>(qc, cls_token,
                                                          pos_embed, hbuf);

  float* h = hbuf;
  float* acc = accb;
  for (int l = 0; l < NLAYER; ++l) {
    hipMemsetAsync(acc, 0, (size_t)TOK * DIM * sizeof(float), stream);
    hipMemsetAsync(cnt_eb, 0, 256 * sizeof(int), stream);
    k_router<<<TOK, 64, 0, stream>>>(h, router_w + (size_t)l * DIM * NEXP,
                                     router_b + (size_t)l * NEXP, cnt_eb, tmps,
                                     tmpw);
    k_scan<<<1, 64, 0, stream>>>(cnt_eb, off_eb, off_e, cnt_e);
    k_scatter<<<256, 256, 0, stream>>>(cnt_eb, off_eb, tmps, tmpw, ptok, pwb);
    k_ln_noaff<<<TOK, 256, 0, stream>>>(h, xhat);

    const float* g1 = ln1_g + (size_t)l * NEXP * DIM;
    const float* b1 = ln1_b + (size_t)l * NEXP * DIM;
    const float* Wqkv = qkv_w + (size_t)l * NEXP * DIM * 768;
    const float* Bqkv = qkv_b + (size_t)l * NEXP * 768;

    // Q: gathered rows, all 8 experts, qkv cols [0,256)
    k_gemm_t<64, true><<<dim3(4, YB, 8), 256, 0, stream>>>(
        xhat, Wqkv, Bqkv, g1, b1, nullptr, nullptr, nullptr, ptok, off_e,
        cnt_e, qc, 0, DIM, DIM, 768, 0, 768, 0, 0, 3);

    // K/V dense (all tokens) for 4 experts at a time (buffer aliased w/ ffc)
    for (int grp = 0; grp < 2; ++grp) {
      int eb0 = grp * 4;
      k_gemm_t<128, true><<<dim3(8, YB128, 4), 256, 0, stream>>>(
          xhat, Wqkv, Bqkv, g1, b1, nullptr, nullptr, nullptr, nullptr,
          nullptr, nullptr, kv4, TOK, 512, DIM, 768, 256, 768, eb0, 0, 0);
      k_attn<<<1024, 256, 0, stream>>>(qc, kv4, oc, cnt_eb, off_eb, eb0);
    }

    // proj (+ residual h), compact rows
    k_gemm_t<64, false><<<dim3(4, YB, 8), 256, 0, stream>>>(
        oc, proj_w + (size_t)l * NEXP * DIM * DIM,
        proj_b + (size_t)l * NEXP * DIM, nullptr, nullptr, h, nullptr, nullptr,
        ptok, off_e, cnt_e, x2c, 0, DIM, DIM, DIM, 0, DIM, 0, 1, 1);
    k_ln_seg<<<dim3(YB, 8), 256, 0, stream>>>(
        x2c, ln2_g + (size_t)l * NEXP * DIM, ln2_b + (size_t)l * NEXP * DIM,
        hlnc, off_e, cnt_e);
    k_gemm_t<128, false><<<dim3(16, YB128, 8), 256, 0, stream>>>(
        hlnc, fc1_w + (size_t)l * NEXP * DIM * FFDIM,
        fc1_b + (size_t)l * NEXP * FFDIM, nullptr, nullptr, nullptr, nullptr,
        nullptr, ptok, off_e, cnt_e, ffc, 0, FFDIM, DIM, FFDIM, 0, FFDIM, 0, 2,
        1);
    // fc2: weighted scatter-accumulate into acc (2 commutative adds/token)
    k_gemm_t<64, false><<<dim3(4, YB, 8), 256, 0, stream>>>(
        ffc, fc2_w + (size_t)l * NEXP * FFDIM * DIM,
        fc2_b + (size_t)l * NEXP * DIM, nullptr, nullptr, nullptr, x2c, pwb,
        ptok, off_e, cnt_e, acc, 0, DIM, FFDIM, DIM, 0, DIM, 0, 3, 1);
    float* t = h;
    h = acc;
    acc = t;
  }
  k_head<<<BATCH, 256, 0, stream>>>(h, norm_g, norm_b, head_w, head_b,
                                    (float*)d_out);
}

// Round 3
// 3747.573 us; speedup vs baseline: 1.3047x; 1.3047x over previous
//
#include <hip/hip_runtime.h>
#include <math.h>

#define SEQ 197
#define BATCH 32
#define DIM 256
#define NHEAD 8
#define HDIM 32
#define NEXP 8
#define NLAYER 4
#define FFDIM 1024
#define NCLS 1000
#define NPATCH 196
#define TOK (BATCH * SEQ) /* 6304 */
#define CAP 13120         /* 2*TOK + 8*64 segment padding */
#define YB 99             /* ceil(TOK/64) */

// ---------------------------------------------------------------- im2col ----
__global__ __launch_bounds__(256) void k_im2col(const float* __restrict__ x,
                                                float* __restrict__ Apat) {
  int idx = blockIdx.x * 256 + threadIdx.x;
  if (idx >= BATCH * NPATCH * 768) return;
  int cpp = idx % 768;
  int m = idx / 768;
  int n = m % NPATCH;
  int b = m / NPATCH;
  int c = cpp >> 8;
  int py = (cpp >> 4) & 15;
  int px = cpp & 15;
  int gy = n / 14, gx = n % 14;
  Apat[idx] = x[(((size_t)b * 3 + c) * 224 + gy * 16 + py) * 224 + gx * 16 + px];
}

// ------------------------------------------------------------- unified GEMM -
// 64x128x16 tile, 256 threads, 4x8 per thread (two 4-col chunks), simple
// low-VGPR staging (stage->barrier->compute->barrier). blockIdx.z = expert
// slot ez, e = ebase+ez.
// flags bit0 = segmented rows (off_e/cnt_e), bit1 = gather A row via ptok.
// AFF: per-expert affine on A: a = fma(a, gsc[e*K+k], gof[e*K+k]).
// mode 0: out[row] = v            (seg: row=gr; dense: row=ez*M+r)
// mode 1: out[gr]  = v + R[tok]
// mode 2: out[gr]  = gelu(v)
// mode 3: atomicAdd(out[tok], PW[gr]*(X2[gr]+v))
template <bool AFF>
__global__ __launch_bounds__(256) void k_gemm_t(
    const float* __restrict__ A, const float* __restrict__ W,
    const float* __restrict__ bias, const float* __restrict__ gsc,
    const float* __restrict__ gof, const float* __restrict__ R,
    const float* __restrict__ X2, const float* __restrict__ PW,
    const int* __restrict__ ptok, const int* __restrict__ off_e,
    const int* __restrict__ cnt_e, float* __restrict__ out, int M, int N,
    int K, int Wld, int wcol, int bstride, int ebase, int mode, int flags) {
  __shared__ float As[16][68];
  __shared__ float Bs[16][132];
  int ez = blockIdx.z;
  int e = ebase + ez;
  bool seg = (flags & 1) != 0;
  int rows = seg ? cnt_e[e] : M;
  int row0 = blockIdx.y * 64;
  if (row0 >= rows) return;
  int col0 = blockIdx.x * 128;
  int tid = threadIdx.x;
  int base = seg ? off_e[e] : 0;
  const float* Wp = W + (size_t)e * K * Wld + wcol;
  const float* bp = bias + (size_t)e * bstride + wcol;

  // A staging map: one float4 per thread
  int rr = tid >> 2, kq = (tid & 3) * 4;
  int r = row0 + rr;
  bool val = r < rows;
  int rc = val ? r : rows - 1; /* rows >= 1 (row0<rows) */
  int gr0 = base + rc;
  int arow = seg ? ((flags & 2) ? ptok[gr0] : gr0) : rc;
  const float* aptr = A + (size_t)arow * K + kq;
  float msk = val ? 1.f : 0.f;
  const float* gptr = AFF ? gsc + (size_t)e * K + kq : nullptr;
  const float* optr = AFF ? gof + (size_t)e * K + kq : nullptr;
  // B staging map: two float4 per thread
  int bk = tid >> 5;       /* 0..7 */
  int bc = (tid & 31) * 4; /* 0..124 */
  const float* bptr = Wp + (size_t)bk * Wld + col0 + bc;

  int tx = tid & 15, ty = tid >> 4;
  float acc0[4][4] = {};
  float acc1[4][4] = {};
  for (int k0 = 0; k0 < K; k0 += 16) {
    float4 av = *(const float4*)(aptr + k0);
    if (AFF) {
      float4 gv = *(const float4*)(gptr + k0);
      float4 ov = *(const float4*)(optr + k0);
      av.x = fmaf(av.x, gv.x, ov.x);
      av.y = fmaf(av.y, gv.y, ov.y);
      av.z = fmaf(av.z, gv.z, ov.z);
      av.w = fmaf(av.w, gv.w, ov.w);
    }
    As[kq + 0][rr] = av.x * msk;
    As[kq + 1][rr] = av.y * msk;
    As[kq + 2][rr] = av.z * msk;
    As[kq + 3][rr] = av.w * msk;
    const float* bt = bptr + (size_t)k0 * Wld;
    *(float4*)&Bs[bk][bc] = *(const float4*)bt;
    *(float4*)&Bs[bk + 8][bc] = *(const float4*)(bt + (size_t)8 * Wld);
    __syncthreads();
#pragma unroll
    for (int k = 0; k < 16; ++k) {
      float4 a = *(const float4*)&As[k][ty * 4];
      float4 b0 = *(const float4*)&Bs[k][tx * 4];
      float4 b1 = *(const float4*)&Bs[k][64 + tx * 4];
      float aa[4] = {a.x, a.y, a.z, a.w};
      float b0a[4] = {b0.x, b0.y, b0.z, b0.w};
      float b1a[4] = {b1.x, b1.y, b1.z, b1.w};
#pragma unroll
      for (int i = 0; i < 4; ++i) {
#pragma unroll
        for (int j = 0; j < 4; ++j) {
          acc0[i][j] = fmaf(aa[i], b0a[j], acc0[i][j]);
          acc1[i][j] = fmaf(aa[i], b1a[j], acc1[i][j]);
        }
      }
    }
    __syncthreads();
  }
  // epilogue
#pragma unroll
  for (int i = 0; i < 4; ++i) {
    int rrow = row0 + ty * 4 + i;
    if (rrow >= rows) continue;
    int gr = base + rrow;
#pragma unroll
    for (int c = 0; c < 2; ++c) {
#pragma unroll
      for (int j = 0; j < 4; ++j) {
        int col = col0 + c * 64 + tx * 4 + j;
        float v = (c ? acc1[i][j] : acc0[i][j]) + bp[col];
        if (mode == 0) {
          size_t orow = seg ? (size_t)gr : (size_t)ez * M + rrow;
          out[orow * N + col] = v;
        } else if (mode == 1) {
          int t = ptok[gr];
          out[(size_t)gr * N + col] = v + R[(size_t)t * N + col];
        } else if (mode == 2) {
          out[(size_t)gr * N + col] =
              0.5f * v * (1.f + erff(v * 0.70710678118654752f));
        } else {
          int t = ptok[gr];
          atomicAdd(&out[(size_t)t * N + col],
                    PW[gr] * (X2[(size_t)gr * N + col] + v));
        }
      }
    }
  }
}

// ------------------------------------------------------------- assemble h ---
__global__ __launch_bounds__(256) void k_assemble(const float* __restrict__ tmp,
                                                  const float* __restrict__ cls,
                                                  const float* __restrict__ pos,
                                                  float* __restrict__ h) {
  int idx = blockIdx.x * 256 + threadIdx.x;
  if (idx >= TOK * DIM) return;
  int d = idx & 255;
  int t = idx >> 8;
  int s = t % SEQ;
  int b = t / SEQ;
  float v = (s == 0) ? cls[d] : tmp[((size_t)b * NPATCH + s - 1) * DIM + d];
  h[idx] = v + pos[s * DIM + d];
}

// ------------------------------------------------------------------ router --
__global__ __launch_bounds__(64) void k_router(
    const float* __restrict__ h, const float* __restrict__ rw,
    const float* __restrict__ rb, int* __restrict__ cnt_eb,
    int* __restrict__ tmp_s, float* __restrict__ tmp_w) {
  int t = blockIdx.x;
  int lane = threadIdx.x;
  float hv[4];
  const float* hp = h + (size_t)t * DIM + lane * 4;
#pragma unroll
  for (int i = 0; i < 4; i++) hv[i] = hp[i];
  float lg[8];
#pragma unroll
  for (int e = 0; e < 8; e++) {
    float p = 0.f;
#pragma unroll
    for (int i = 0; i < 4; i++) p = fmaf(hv[i], rw[(lane * 4 + i) * 8 + e], p);
#pragma unroll
    for (int off = 32; off; off >>= 1) p += __shfl_down(p, off);
    lg[e] = p;
  }
  if (lane == 0) {
#pragma unroll
    for (int e = 0; e < 8; e++) lg[e] += rb[e];
    float mx = lg[0];
#pragma unroll
    for (int e = 1; e < 8; e++) mx = fmaxf(mx, lg[e]);
    float pr[8];
#pragma unroll
    for (int e = 0; e < 8; e++) pr[e] = expf(lg[e] - mx);
    int i0 = 0;
#pragma unroll
    for (int e = 1; e < 8; e++)
      if (pr[e] > pr[i0]) i0 = e;
    int i1 = -1;
#pragma unroll
    for (int e = 0; e < 8; e++)
      if (e != i0 && (i1 < 0 || pr[e] > pr[i1])) i1 = e;
    float wsum = pr[i0] + pr[i1];
    int b = t / SEQ, s = t - b * SEQ;
    int eb0 = i0 * 32 + b;
    int p0 = atomicAdd(&cnt_eb[eb0], 1);
    tmp_s[eb0 * SEQ + p0] = s;
    tmp_w[eb0 * SEQ + p0] = pr[i0] / wsum;
    int eb1 = i1 * 32 + b;
    int p1 = atomicAdd(&cnt_eb[eb1], 1);
    tmp_s[eb1 * SEQ + p1] = s;
    tmp_w[eb1 * SEQ + p1] = pr[i1] / wsum;
  }
}

// --------------------------------------------------------------- scan -------
__global__ __launch_bounds__(64) void k_scan(const int* __restrict__ cnt_eb,
                                             int* __restrict__ off_eb,
                                             int* __restrict__ off_e,
                                             int* __restrict__ cnt_e) {
  if (threadIdx.x == 0 && blockIdx.x == 0) {
    int g = 0;
    for (int e = 0; e < 8; e++) {
      off_e[e] = g;
      int ce = 0;
      for (int b = 0; b < 32; b++) {
        off_eb[e * 32 + b] = g + ce;
        ce += cnt_eb[e * 32 + b];
      }
      cnt_e[e] = ce;
      g += (ce + 63) & ~63;
    }
  }
}

__global__ __launch_bounds__(256) void k_scatter(
    const int* __restrict__ cnt_eb, const int* __restrict__ off_eb,
    const int* __restrict__ tmp_s, const float* __restrict__ tmp_w,
    int* __restrict__ ptok, float* __restrict__ pw) {
  int eb = blockIdx.x;
  int b = eb & 31;
  int c = cnt_eb[eb];
  int o = off_eb[eb];
  for (int i = threadIdx.x; i < c; i += 256) {
    ptok[o + i] = b * SEQ + tmp_s[eb * SEQ + i];
    pw[o + i] = tmp_w[eb * SEQ + i];
  }
}

// -------------------------------------------------------------- layernorm ---
__global__ __launch_bounds__(256) void k_ln_noaff(const float* __restrict__ X,
                                                  float* __restrict__ Y) {
  int t = blockIdx.x;
  int d = threadIdx.x;
  float v = X[(size_t)t * DIM + d];
  __shared__ float red[4];
  float s = v;
#pragma unroll
  for (int o = 32; o; o >>= 1) s += __shfl_down(s, o);
  if ((d & 63) == 0) red[d >> 6] = s;
  __syncthreads();
  float mean = (red[0] + red[1] + red[2] + red[3]) * (1.f / 256.f);
  __syncthreads();
  float c = v - mean;
  float s2 = c * c;
#pragma unroll
  for (int o = 32; o; o >>= 1) s2 += __shfl_down(s2, o);
  if ((d & 63) == 0) red[d >> 6] = s2;
  __syncthreads();
  float var = (red[0] + red[1] + red[2] + red[3]) * (1.f / 256.f);
  Y[(size_t)t * DIM + d] = c * rsqrtf(var + 1e-5f);
}

__global__ __launch_bounds__(256) void k_ln_seg(
    const float* __restrict__ X, const float* __restrict__ g,
    const float* __restrict__ bta, float* __restrict__ Y,
    const int* __restrict__ off_e, const int* __restrict__ cnt_e) {
  int e = blockIdx.y;
  int cnt = cnt_e[e];
  int base = off_e[e];
  int d = threadIdx.x;
  float gv = g[e * DIM + d];
  float bv = bta[e * DIM + d];
  __shared__ float red[4];
  for (int r = blockIdx.x; r < cnt; r += gridDim.x) {
    size_t gr = (size_t)(base + r);
    float v = X[gr * DIM + d];
    float s = v;
#pragma unroll
    for (int o = 32; o; o >>= 1) s += __shfl_down(s, o);
    if ((d & 63) == 0) red[d >> 6] = s;
    __syncthreads();
    float mean = (red[0] + red[1] + red[2] + red[3]) * (1.f / 256.f);
    __syncthreads();
    float c = v - mean;
    float s2 = c * c;
#pragma unroll
    for (int o = 32; o; o >>= 1) s2 += __shfl_down(s2, o);
    if ((d & 63) == 0) red[d >> 6] = s2;
    __syncthreads();
    float var = (red[0] + red[1] + red[2] + red[3]) * (1.f / 256.f);
    Y[gr * DIM + d] = c * rsqrtf(var + 1e-5f) * gv + bv;
    __syncthreads();
  }
}

// -------------------------------------------------------------- attention ---
__global__ __launch_bounds__(256) void k_attn(
    const float* __restrict__ qc, const float* __restrict__ kv,
    float* __restrict__ oc, const int* __restrict__ cnt_eb,
    const int* __restrict__ off_eb, int ebase) {
  int bx = blockIdx.x;
  int hh = bx & 7;
  int b = (bx >> 3) & 31;
  int ez = bx >> 8;
  int eb = (ebase + ez) * 32 + b;
  int cnt = cnt_eb[eb];
  if (cnt == 0) return;
  int off = off_eb[eb];
  __shared__ float Ks[SEQ][HDIM];
  __shared__ float Vs[SEQ][HDIM];
  const float* base = kv + ((size_t)ez * TOK + (size_t)b * SEQ) * 512;
  int tid = threadIdx.x;
  for (int i = tid; i < SEQ * 8; i += 256) {
    int row = i >> 3, c4 = (i & 7) * 4;
    const float* kp = base + (size_t)row * 512 + hh * HDIM + c4;
    *(float4*)&Ks[row][c4] = *(const float4*)kp;
    *(float4*)&Vs[row][c4] = *(const float4*)(kp + 256);
  }
  __syncthreads();
  int q = tid;
  if (q >= cnt) return;
  float qv[HDIM];
  const float* qp = qc + (size_t)(off + q) * DIM + hh * HDIM;
#pragma unroll
  for (int i = 0; i < 8; i++) {
    float4 t = *(const float4*)(qp + i * 4);
    qv[i * 4 + 0] = t.x;
    qv[i * 4 + 1] = t.y;
    qv[i * 4 + 2] = t.z;
    qv[i * 4 + 3] = t.w;
  }
  float m = -1e30f, l = 0.f;
  float acc[HDIM] = {};
  for (int j = 0; j < SEQ; ++j) {
    float s = 0.f;
#pragma unroll
    for (int d = 0; d < HDIM; ++d) s = fmaf(qv[d], Ks[j][d], s);
    s *= 0.17677669529663687f; /* 1/sqrt(32) */
    float e2;
    if (s > m) {
      float f = expf(m - s);
      l *= f;
#pragma unroll
      for (int d = 0; d < HDIM; ++d) acc[d] *= f;
      m = s;
      e2 = 1.f;
    } else {
      e2 = expf(s - m);
    }
    l += e2;
#pragma unroll
    for (int d = 0; d < HDIM; ++d) acc[d] = fmaf(e2, Vs[j][d], acc[d]);
  }
  float inv = 1.f / l;
  float* op = oc + (size_t)(off + q) * DIM + hh * HDIM;
#pragma unroll
  for (int i = 0; i < 8; i++) {
    float4 t;
    t.x = acc[i * 4 + 0] * inv;
    t.y = acc[i * 4 + 1] * inv;
    t.z = acc[i * 4 + 2] * inv;
    t.w = acc[i * 4 + 3] * inv;
    *(float4*)(op + i * 4) = t;
  }
}

// ------------------------------------------------------------- final head ---
__global__ __launch_bounds__(256) void k_head(const float* __restrict__ h,
                                              const float* __restrict__ ng,
                                              const float* __restrict__ nb,
                                              const float* __restrict__ hw,
                                              const float* __restrict__ hb,
                                              float* __restrict__ out) {
  int b = blockIdx.x;
  int d = threadIdx.x;
  float v = h[(size_t)b * SEQ * DIM + d];
  __shared__ float red[4];
  __shared__ float hls[DIM];
  float s = v;
#pragma unroll
  for (int off = 32; off; off >>= 1) s += __shfl_down(s, off);
  if ((d & 63) == 0) red[d >> 6] = s;
  __syncthreads();
  float mean = (red[0] + red[1] + red[2] + red[3]) * (1.f / 256.f);
  __syncthreads();
  float c = v - mean;
  float s2 = c * c;
#pragma unroll
  for (int off = 32; off; off >>= 1) s2 += __shfl_down(s2, off);
  if ((d & 63) == 0) red[d >> 6] = s2;
  __syncthreads();
  float var = (red[0] + red[1] + red[2] + red[3]) * (1.f / 256.f);
  hls[d] = c * rsqrtf(var + 1e-5f) * ng[d] + nb[d];
  __syncthreads();
  for (int j = d; j < NCLS; j += 256) {
    float sdot = hb[j];
    for (int k2 = 0; k2 < DIM; k2++)
      sdot = fmaf(hls[k2], hw[(size_t)k2 * NCLS + j], sdot);
    out[(size_t)b * NCLS + j] = sdot;
  }
}

// ---------------------------------------------------------------- launch ----
extern "C" void kernel_launch(void* const* d_in, const int* in_sizes, int n_in,
                              void* d_out, int out_size, void* d_ws,
                              size_t ws_size, hipStream_t stream) {
  const float* x = (const float*)d_in[0];
  const float* patch_w = (const float*)d_in[1];
  const float* patch_b = (const float*)d_in[2];
  const float* cls_token = (const float*)d_in[3];
  const float* pos_embed = (const float*)d_in[4];
  const float* router_w = (const float*)d_in[5];
  const float* router_b = (const float*)d_in[6];
  const float* ln1_g = (const float*)d_in[7];
  const float* ln1_b = (const float*)d_in[8];
  const float* qkv_w = (const float*)d_in[9];
  const float* qkv_b = (const float*)d_in[10];
  const float* proj_w = (const float*)d_in[11];
  const float* proj_b = (const float*)d_in[12];
  const float* ln2_g = (const float*)d_in[13];
  const float* ln2_b = (const float*)d_in[14];
  const float* fc1_w = (const float*)d_in[15];
  const float* fc1_b = (const float*)d_in[16];
  const float* fc2_w = (const float*)d_in[17];
  const float* fc2_b = (const float*)d_in[18];
  const float* norm_g = (const float*)d_in[19];
  const float* norm_b = (const float*)d_in[20];
  const float* head_w = (const float*)d_in[21];
  const float* head_b = (const float*)d_in[22];

  float* ws = (float*)d_ws;
  size_t off = 0;
  float* xhat = ws + off; off += (size_t)TOK * DIM;
  float* hbuf = ws + off; off += (size_t)TOK * DIM;
  float* accb = ws + off; off += (size_t)TOK * DIM;
  float* qc   = ws + off; off += (size_t)CAP * DIM;   /* also hln (aliased) */
  float* oc   = ws + off; off += (size_t)CAP * DIM;
  float* x2c  = ws + off; off += (size_t)CAP * DIM;
  float* ffc  = ws + off; off += (size_t)CAP * FFDIM; /* also im2col + kv4 */
  float* pwb  = ws + off; off += CAP;
  float* tmpw = ws + off; off += 256 * SEQ;
  int* ptok   = (int*)(ws + off); off += CAP;
  int* tmps   = (int*)(ws + off); off += 256 * SEQ;
  int* cnt_eb = (int*)(ws + off); off += 256;
  int* off_eb = (int*)(ws + off); off += 256;
  int* off_e  = (int*)(ws + off); off += 8;
  int* cnt_e  = (int*)(ws + off); off += 8;
  float* kv4 = ffc;   /* 4*TOK*512 = 12.9M floats <= CAP*FFDIM = 13.4M */
  float* hlnc = qc;   /* qc dead after attention; hln live ln2->fc1 */

  // ---- patch embed ----
  int tot = BATCH * NPATCH * 768;
  k_im2col<<<(tot + 255) / 256, 256, 0, stream>>>(x, ffc);
  k_gemm_t<false><<<dim3(2, 98, 1), 256, 0, stream>>>(
      ffc, patch_w, patch_b, nullptr, nullptr, nullptr, nullptr, nullptr,
      nullptr, nullptr, nullptr, qc, BATCH * NPATCH, DIM, 768, DIM, 0, 0, 0, 0,
      0);
  k_assemble<<<(TOK * DIM + 255) / 256, 256, 0, stream>>>(qc, cls_token,
                                                          pos_embed, hbuf);

  float* h = hbuf;
  float* acc = accb;
  for (int l = 0; l < NLAYER; ++l) {
    hipMemsetAsync(acc, 0, (size_t)TOK * DIM * sizeof(float), stream);
    hipMemsetAsync(cnt_eb, 0, 256 * sizeof(int), stream);
    k_router<<<TOK, 64, 0, stream>>>(h, router_w + (size_t)l * DIM * NEXP,
                                     router_b + (size_t)l * NEXP, cnt_eb, tmps,
                                     tmpw);
    k_scan<<<1, 64, 0, stream>>>(cnt_eb, off_eb, off_e, cnt_e);
    k_scatter<<<256, 256, 0, stream>>>(cnt_eb, off_eb, tmps, tmpw, ptok, pwb);
    k_ln_noaff<<<TOK, 256, 0, stream>>>(h, xhat);

    const float* g1 = ln1_g + (size_t)l * NEXP * DIM;
    const float* b1 = ln1_b + (size_t)l * NEXP * DIM;
    const float* Wqkv = qkv_w + (size_t)l * NEXP * DIM * 768;
    const float* Bqkv = qkv_b + (size_t)l * NEXP * 768;

    // Q: gathered rows, all 8 experts, qkv cols [0,256)
    k_gemm_t<true><<<dim3(2, YB, 8), 256, 0, stream>>>(
        xhat, Wqkv, Bqkv, g1, b1, nullptr, nullptr, nullptr, ptok, off_e,
        cnt_e, qc, 0, DIM, DIM, 768, 0, 768, 0, 0, 3);

    // K/V dense (all tokens) for 4 experts at a time (buffer aliased w/ ffc)
    for (int grp = 0; grp < 2; ++grp) {
      int eb0 = grp * 4;
      k_gemm_t<true><<<dim3(4, YB, 4), 256, 0, stream>>>(
          xhat, Wqkv, Bqkv, g1, b1, nullptr, nullptr, nullptr, nullptr,
          nullptr, nullptr, kv4, TOK, 512, DIM, 768, 256, 768, eb0, 0, 0);
      k_attn<<<1024, 256, 0, stream>>>(qc, kv4, oc, cnt_eb, off_eb, eb0);
    }

    // proj (+ residual h), compact rows
    k_gemm_t<false><<<dim3(2, YB, 8), 256, 0, stream>>>(
        oc, proj_w + (size_t)l * NEXP * DIM * DIM,
        proj_b + (size_t)l * NEXP * DIM, nullptr, nullptr, h, nullptr, nullptr,
        ptok, off_e, cnt_e, x2c, 0, DIM, DIM, DIM, 0, DIM, 0, 1, 1);
    k_ln_seg<<<dim3(YB, 8), 256, 0, stream>>>(
        x2c, ln2_g + (size_t)l * NEXP * DIM, ln2_b + (size_t)l * NEXP * DIM,
        hlnc, off_e, cnt_e);
    k_gemm_t<false><<<dim3(8, YB, 8), 256, 0, stream>>>(
        hlnc, fc1_w + (size_t)l * NEXP * DIM * FFDIM,
        fc1_b + (size_t)l * NEXP * FFDIM, nullptr, nullptr, nullptr, nullptr,
        nullptr, ptok, off_e, cnt_e, ffc, 0, FFDIM, DIM, FFDIM, 0, FFDIM, 0, 2,
        1);
    // fc2: weighted scatter-accumulate into acc (2 commutative adds/token)
    k_gemm_t<false><<<dim3(2, YB, 8), 256, 0, stream>>>(
        ffc, fc2_w + (size_t)l * NEXP * FFDIM * DIM,
        fc2_b + (size_t)l * NEXP * DIM, nullptr, nullptr, nullptr, x2c, pwb,
        ptok, off_e, cnt_e, acc, 0, DIM, FFDIM, DIM, 0, DIM, 0, 3, 1);
    float* t = h;
    h = acc;
    acc = t;
  }
  k_head<<<BATCH, 256, 0, stream>>>(h, norm_g, norm_b, head_w, head_b,
                                    (float*)d_out);
}